// Round 2
// baseline (1051.900 us; speedup 1.0000x reference)
//
#include <hip/hip_runtime.h>

#define TT 1024
#define DD 256
#define HH 512
#define CB 32              // batches per chunk
#define CM (CB * TT)       // rows per chunk = 32768

__device__ __forceinline__ double shfl_xor_d(double x, int m) {
    union { double d; unsigned int u[2]; } a; a.d = x;
    a.u[0] = __shfl_xor(a.u[0], m);
    a.u[1] = __shfl_xor(a.u[1], m);
    return a.d;
}

// ---------------------------------------------------------------------------
// Kernel 0: transpose weights to k-major (fp32; weights are exact inputs).
// ---------------------------------------------------------------------------
__global__ __launch_bounds__(256) void transpose_w(const float* __restrict__ W1,
                                                   const float* __restrict__ W2,
                                                   float* __restrict__ W1T,
                                                   float* __restrict__ W2T) {
    int i = blockIdx.x * 256 + threadIdx.x;   // 512*256 = 131072
    {
        int k = i >> 9;
        int h = i & 511;
        W1T[i] = W1[h * DD + k];
    }
    {
        int h = i >> 8;
        int d = i & 255;
        W2T[i] = W2[d * HH + h];
    }
}

// ---------------------------------------------------------------------------
// Kernel 1: GEMM1 (x @ W1^T + b1) + LayerNorm, fp64 accumulate/stats.
// 512 thr = 8 waves; BM=32 (wave tr owns rows tr*4..+3); lane tc owns cols
// {tc*4..+3, 256+tc*4..+3}. Full row in one wave -> shfl reduce for stats.
// ---------------------------------------------------------------------------
__global__ __launch_bounds__(512) void gemm1_ln_f64(const float* __restrict__ X,
                                                    const float* __restrict__ W1T,
                                                    const float* __restrict__ b1,
                                                    const float* __restrict__ g1,
                                                    const float* __restrict__ be1,
                                                    double* __restrict__ Hn) {
    __shared__ float As[32][16];
    __shared__ float Ws[16][512];
    const int tid = threadIdx.x;
    const int tc = tid & 63;
    const int tr = tid >> 6;
    const int m0 = blockIdx.x * 32;

    double acc[4][8];
#pragma unroll
    for (int r = 0; r < 4; ++r)
#pragma unroll
        for (int c = 0; c < 8; ++c) acc[r][c] = 0.0;

    const int arow = tid >> 4;     // 0..31
    const int ak   = tid & 15;     // 0..15

    for (int kc = 0; kc < 16; ++kc) {
        __syncthreads();
        As[arow][ak] = X[(size_t)(m0 + arow) * DD + kc * 16 + ak];
#pragma unroll
        for (int j = 0; j < 4; ++j) {
            int f4  = tid + 512 * j;      // 0..2047
            int row = f4 >> 7;
            int c4  = f4 & 127;
            *(float4*)&Ws[row][c4 * 4] =
                *(const float4*)(W1T + (size_t)(kc * 16 + row) * HH + c4 * 4);
        }
        __syncthreads();
#pragma unroll
        for (int kb = 0; kb < 4; ++kb) {
            float4 a4[4];
#pragma unroll
            for (int r = 0; r < 4; ++r)
                a4[r] = *(const float4*)&As[tr * 4 + r][kb * 4];
#pragma unroll
            for (int kk = 0; kk < 4; ++kk) {
                float4 w0 = *(const float4*)&Ws[kb * 4 + kk][tc * 4];
                float4 w1 = *(const float4*)&Ws[kb * 4 + kk][256 + tc * 4];
                double wd[8];
                wd[0] = (double)w0.x; wd[1] = (double)w0.y;
                wd[2] = (double)w0.z; wd[3] = (double)w0.w;
                wd[4] = (double)w1.x; wd[5] = (double)w1.y;
                wd[6] = (double)w1.z; wd[7] = (double)w1.w;
#pragma unroll
                for (int r = 0; r < 4; ++r) {
                    double ad = (double)(((const float*)&a4[r])[kk]);
#pragma unroll
                    for (int c = 0; c < 8; ++c)
                        acc[r][c] = fma(ad, wd[c], acc[r][c]);
                }
            }
        }
    }

    double b1v[8], g1v[8], be1v[8];
#pragma unroll
    for (int half = 0; half < 2; ++half)
#pragma unroll
        for (int jj = 0; jj < 4; ++jj) {
            int col = half * 256 + tc * 4 + jj;
            b1v[half * 4 + jj]  = (double)b1[col];
            g1v[half * 4 + jj]  = (double)g1[col];
            be1v[half * 4 + jj] = (double)be1[col];
        }
#pragma unroll
    for (int r = 0; r < 4; ++r) {
        double v[8];
        double s = 0.0;
#pragma unroll
        for (int i = 0; i < 8; ++i) { v[i] = acc[r][i] + b1v[i]; s += v[i]; }
#pragma unroll
        for (int off = 32; off > 0; off >>= 1) s += shfl_xor_d(s, off);
        double mu = s * (1.0 / 512.0);
        double q = 0.0;
#pragma unroll
        for (int i = 0; i < 8; ++i) { double d = v[i] - mu; q += d * d; }
#pragma unroll
        for (int off = 32; off > 0; off >>= 1) q += shfl_xor_d(q, off);
        double inv = 1.0 / sqrt(q * (1.0 / 512.0) + 1e-5);
        double* dst = Hn + (size_t)(m0 + tr * 4 + r) * HH;
#pragma unroll
        for (int i = 0; i < 4; ++i)
            dst[tc * 4 + i] = (v[i] - mu) * inv * g1v[i] + be1v[i];
#pragma unroll
        for (int i = 0; i < 4; ++i)
            dst[256 + tc * 4 + i] = (v[4 + i] - mu) * inv * g1v[4 + i] + be1v[4 + i];
    }
}

// ---------------------------------------------------------------------------
// Kernel 2: LIF over T (fp64 recurrence), one lane per (b,h). PF depth 16.
// ---------------------------------------------------------------------------
__global__ __launch_bounds__(64) void lif1_f64(const double* __restrict__ Hn,
                                               unsigned char* __restrict__ S) {
    int b = blockIdx.x >> 3;                       // 0..31
    int h = (blockIdx.x & 7) * 64 + threadIdx.x;   // 0..511
    const double* src = Hn + (size_t)b * TT * HH + h;
    unsigned char* dst = S + (size_t)b * TT * HH + h;
    double v = 0.0;
    double cur[16];
#pragma unroll
    for (int j = 0; j < 16; ++j) cur[j] = src[(size_t)j * HH];
    for (int g = 0; g < 64; ++g) {
        double nxt[16];
        if (g < 63) {
#pragma unroll
            for (int j = 0; j < 16; ++j) nxt[j] = src[(size_t)(g * 16 + 16 + j) * HH];
        }
#pragma unroll
        for (int j = 0; j < 16; ++j) {
            v = v + (cur[j] - v) * 0.5;
            bool sp = (v >= 1.0);
            dst[(size_t)(g * 16 + j) * HH] = sp ? (unsigned char)1 : (unsigned char)0;
            if (sp) v = 0.0;
        }
        if (g < 63) {
#pragma unroll
            for (int j = 0; j < 16; ++j) cur[j] = nxt[j];
        }
    }
}

// ---------------------------------------------------------------------------
// Kernel 3: GEMM2 (spikes @ W2^T + b2) + LayerNorm over 256, fp64.
// 512 thr; BM=32, BK=32; lane tc owns cols tc*4..+3 (full row in wave).
// ---------------------------------------------------------------------------
__global__ __launch_bounds__(512) void gemm2_ln_f64(const unsigned char* __restrict__ S,
                                                    const float* __restrict__ W2T,
                                                    const float* __restrict__ b2,
                                                    const float* __restrict__ g2,
                                                    const float* __restrict__ be2,
                                                    double* __restrict__ Yn) {
    __shared__ float As[32][32];
    __shared__ float Ws[32][256];
    const int tid = threadIdx.x;
    const int tc = tid & 63;
    const int tr = tid >> 6;
    const int m0 = blockIdx.x * 32;

    double acc[4][4];
#pragma unroll
    for (int r = 0; r < 4; ++r)
#pragma unroll
        for (int c = 0; c < 4; ++c) acc[r][c] = 0.0;

    const int arow = tid >> 4;        // 0..31
    const int ac2  = (tid & 15) * 2;  // 0,2..30

    for (int kc = 0; kc < 16; ++kc) {
        __syncthreads();
        {
            const unsigned char* sp = S + (size_t)(m0 + arow) * HH + kc * 32 + ac2;
            As[arow][ac2]     = (float)sp[0];
            As[arow][ac2 + 1] = (float)sp[1];
        }
#pragma unroll
        for (int j = 0; j < 4; ++j) {
            int f4  = tid + 512 * j;   // 0..2047
            int row = f4 >> 6;         // 0..31
            int c4  = f4 & 63;
            *(float4*)&Ws[row][c4 * 4] =
                *(const float4*)(W2T + (size_t)(kc * 32 + row) * DD + c4 * 4);
        }
        __syncthreads();
#pragma unroll
        for (int kb = 0; kb < 8; ++kb) {
            float4 a4[4];
#pragma unroll
            for (int r = 0; r < 4; ++r)
                a4[r] = *(const float4*)&As[tr * 4 + r][kb * 4];
#pragma unroll
            for (int kk = 0; kk < 4; ++kk) {
                float4 w = *(const float4*)&Ws[kb * 4 + kk][tc * 4];
                double wd[4];
                wd[0] = (double)w.x; wd[1] = (double)w.y;
                wd[2] = (double)w.z; wd[3] = (double)w.w;
#pragma unroll
                for (int r = 0; r < 4; ++r) {
                    double ad = (double)(((const float*)&a4[r])[kk]);
#pragma unroll
                    for (int c = 0; c < 4; ++c)
                        acc[r][c] = fma(ad, wd[c], acc[r][c]);
                }
            }
        }
    }

    double b2v[4], g2v[4], be2v[4];
#pragma unroll
    for (int jj = 0; jj < 4; ++jj) {
        int col = tc * 4 + jj;
        b2v[jj]  = (double)b2[col];
        g2v[jj]  = (double)g2[col];
        be2v[jj] = (double)be2[col];
    }
#pragma unroll
    for (int r = 0; r < 4; ++r) {
        double v[4];
        double s = 0.0;
#pragma unroll
        for (int i = 0; i < 4; ++i) { v[i] = acc[r][i] + b2v[i]; s += v[i]; }
#pragma unroll
        for (int off = 32; off > 0; off >>= 1) s += shfl_xor_d(s, off);
        double mu = s * (1.0 / 256.0);
        double q = 0.0;
#pragma unroll
        for (int i = 0; i < 4; ++i) { double d = v[i] - mu; q += d * d; }
#pragma unroll
        for (int off = 32; off > 0; off >>= 1) q += shfl_xor_d(q, off);
        double inv = 1.0 / sqrt(q * (1.0 / 256.0) + 1e-5);
        double* dst = Yn + (size_t)(m0 + tr * 4 + r) * DD;
#pragma unroll
        for (int i = 0; i < 4; ++i)
            dst[tc * 4 + i] = (v[i] - mu) * inv * g2v[i] + be2v[i];
    }
}

// ---------------------------------------------------------------------------
// Kernel 4: LIF2 (fp64) + residual. out = x + spike.
// ---------------------------------------------------------------------------
__global__ __launch_bounds__(64) void lif2_res_f64(const double* __restrict__ Yn,
                                                   const float* __restrict__ X,
                                                   float* __restrict__ out) {
    int b = blockIdx.x >> 2;                      // 0..31
    int d = (blockIdx.x & 3) * 64 + threadIdx.x;  // 0..255
    const double* src = Yn + (size_t)b * TT * DD + d;
    const float* xs   = X  + (size_t)b * TT * DD + d;
    float* dst        = out + (size_t)b * TT * DD + d;
    double v = 0.0;
    double cur[16];
    float curx[16];
#pragma unroll
    for (int j = 0; j < 16; ++j) {
        cur[j]  = src[(size_t)j * DD];
        curx[j] = xs[(size_t)j * DD];
    }
    for (int g = 0; g < 64; ++g) {
        double nxt[16];
        float nxtx[16];
        if (g < 63) {
#pragma unroll
            for (int j = 0; j < 16; ++j) {
                nxt[j]  = src[(size_t)(g * 16 + 16 + j) * DD];
                nxtx[j] = xs[(size_t)(g * 16 + 16 + j) * DD];
            }
        }
#pragma unroll
        for (int j = 0; j < 16; ++j) {
            v = v + (cur[j] - v) * 0.5;
            bool sp = (v >= 1.0);
            dst[(size_t)(g * 16 + j) * DD] = curx[j] + (sp ? 1.0f : 0.0f);
            if (sp) v = 0.0;
        }
        if (g < 63) {
#pragma unroll
            for (int j = 0; j < 16; ++j) { cur[j] = nxt[j]; curx[j] = nxtx[j]; }
        }
    }
}

extern "C" void kernel_launch(void* const* d_in, const int* in_sizes, int n_in,
                              void* d_out, int out_size, void* d_ws, size_t ws_size,
                              hipStream_t stream) {
    const float* x   = (const float*)d_in[0];
    const float* W1  = (const float*)d_in[1];
    const float* b1  = (const float*)d_in[2];
    const float* g1  = (const float*)d_in[3];
    const float* be1 = (const float*)d_in[4];
    const float* W2  = (const float*)d_in[5];
    const float* b2  = (const float*)d_in[6];
    const float* g2  = (const float*)d_in[7];
    const float* be2 = (const float*)d_in[8];
    float* out = (float*)d_out;

    char* ws = (char*)d_ws;
    float* W1T = (float*)ws;                                    // 512 KB
    float* W2T = (float*)(ws + (512u << 10));                   // 512 KB
    double* Hn = (double*)(ws + (1u << 20));                    // 128 MB (chunk)
    unsigned char* S = (unsigned char*)(ws + (1u << 20) + (128u << 20)); // 16 MB
    double* Yn = (double*)(ws + (1u << 20) + (144u << 20));     // 64 MB (chunk)
    // total: 209 MB

    transpose_w<<<dim3(512), dim3(256), 0, stream>>>(W1, W2, W1T, W2T);

    for (int c = 0; c < 2; ++c) {
        const float* xc = x + (size_t)c * CM * DD;
        float* outc = out + (size_t)c * CM * DD;
        gemm1_ln_f64<<<dim3(CM / 32), dim3(512), 0, stream>>>(xc, W1T, b1, g1, be1, Hn);
        lif1_f64<<<dim3(CB * (HH / 64)), dim3(64), 0, stream>>>(Hn, S);
        gemm2_ln_f64<<<dim3(CM / 32), dim3(512), 0, stream>>>(S, W2T, b2, g2, be2, Yn);
        lif2_res_f64<<<dim3(CB * (DD / 64)), dim3(64), 0, stream>>>(Yn, xc, outc);
    }
}

// Round 3
// 663.619 us; speedup vs baseline: 1.5851x; 1.5851x over previous
//
#include <hip/hip_runtime.h>

typedef int v4i  __attribute__((ext_vector_type(4)));
typedef int v16i __attribute__((ext_vector_type(16)));

#define TT 1024
#define DD 256
#define HH 512
#define CB 32
#define CM (CB*TT)   // 32768 rows per chunk

__device__ __forceinline__ double shfl_xor_d(double x, int m) {
    union { double d; int u[2]; } a; a.d = x;
    a.u[0] = __shfl_xor(a.u[0], m);
    a.u[1] = __shfl_xor(a.u[1], m);
    return a.d;
}

// ---------------------------------------------------------------------------
// prep_w: split W1 [512][256] and W2 [256][512] into 5 signed-digit i8 planes.
// w = sum_j d_j * 2^(-10-7j), d via truncation, |d|<=127. Layout keeps native
// row-major (rows are the MFMA B-operand n-dim, k contiguous).
// ---------------------------------------------------------------------------
__global__ __launch_bounds__(256) void prep_w_k(const float* __restrict__ W1,
                                                const float* __restrict__ W2,
                                                signed char* __restrict__ W1p,
                                                signed char* __restrict__ W2p) {
    int i = blockIdx.x * 256 + threadIdx.x;   // 0..131071
    {
        double a = (double)W1[i];
        double inv = 1024.0, s = 1.0 / 1024.0;
#pragma unroll
        for (int p = 0; p < 5; ++p) {
            int d = (int)(a * inv);
            a -= d * s;
            W1p[(size_t)p * 131072 + i] = (signed char)d;
            inv *= 128.0; s *= (1.0 / 128.0);
        }
    }
    {
        double a = (double)W2[i];
        double inv = 1024.0, s = 1.0 / 1024.0;
#pragma unroll
        for (int p = 0; p < 5; ++p) {
            int d = (int)(a * inv);
            a -= d * s;
            W2p[(size_t)p * 131072 + i] = (signed char)d;
            inv *= 128.0; s *= (1.0 / 128.0);
        }
    }
}

// ---------------------------------------------------------------------------
// split_x: x chunk [CM][256] f32 -> 5 digit planes i8, x = sum d_i 2^(-3-7i).
// ---------------------------------------------------------------------------
__global__ __launch_bounds__(256) void split_x_k(const float* __restrict__ xc,
                                                 signed char* __restrict__ Xp) {
    int gid = blockIdx.x * 256 + threadIdx.x;   // 0 .. CM*64-1
    int e0 = gid * 4;
    float4 xv = *(const float4*)(xc + e0);
    float fa[4] = {xv.x, xv.y, xv.z, xv.w};
    int dg[4][5];
#pragma unroll
    for (int e = 0; e < 4; ++e) {
        double a = (double)fa[e];
        double inv = 8.0, s = 0.125;
#pragma unroll
        for (int p = 0; p < 5; ++p) {
            int d = (int)(a * inv);
            a -= d * s;
            dg[e][p] = d;
            inv *= 128.0; s *= (1.0 / 128.0);
        }
    }
#pragma unroll
    for (int p = 0; p < 5; ++p) {
        int pk = (dg[0][p] & 255) | ((dg[1][p] & 255) << 8) |
                 ((dg[2][p] & 255) << 16) | ((dg[3][p] & 255) << 24);
        *(int*)(Xp + (size_t)p * ((size_t)CM * 256) + e0) = pk;
    }
}

// ---------------------------------------------------------------------------
// GEMM1: H = x @ W1^T + b1, then LayerNorm(512), all exact-i8 Ozaki + fp64.
// Block: 32 rows x 512 cols, 512 thr = 8 waves (1m x 8n), wave = 32x64 (2 nt).
// 5 i32 accumulator banks (one per g=i+j), 15 plane-pairs, K=256.
// ---------------------------------------------------------------------------
__global__ __launch_bounds__(512, 2) void gemm1_i8(
    const signed char* __restrict__ Xp, const signed char* __restrict__ W1p,
    const float* __restrict__ b1, const float* __restrict__ g1,
    const float* __restrict__ be1, double* __restrict__ Hn) {
    __shared__ signed char Asm[5 * 32 * 256];       // 40960 B, swizzled
    __shared__ signed char Bsm[2][512 * 80];        // 81920 B, [h][k64] pad 80
    __shared__ double RS[8][32], RQ[8][32];
    __shared__ double MUs[32], IVs[32];

    const int tid = threadIdx.x;
    const int wave = tid >> 6, lane = tid & 63, lrow = lane & 31, lhalf = lane >> 5;
    const int m0 = blockIdx.x * 32;

    v16i acc[5][2];
#pragma unroll
    for (int g = 0; g < 5; ++g)
#pragma unroll
        for (int nt = 0; nt < 2; ++nt)
#pragma unroll
            for (int r = 0; r < 16; ++r) acc[g][nt][r] = 0;

    // stage A: 5 planes x [32][256], XOR-swizzled
#pragma unroll
    for (int t = 0; t < 5; ++t) {
        int idx = tid + t * 512;
        int p = idx >> 9, r = (idx >> 4) & 31, k16 = (idx & 15) << 4;
        v4i v = *(const v4i*)(Xp + (size_t)p * ((size_t)CM * 256) +
                              (size_t)(m0 + r) * 256 + k16);
        *(v4i*)&Asm[p * 8192 + r * 256 + (k16 ^ ((r & 7) << 4))] = v;
    }

    v4i breg[4];
    {   // prologue load (j=0, kk=0): thread t stages W1p row h=t, 64 bytes
        const signed char* bp = W1p + (size_t)tid * 256;
#pragma unroll
        for (int q = 0; q < 4; ++q) breg[q] = *(const v4i*)(bp + q * 16);
    }

#pragma unroll
    for (int j = 0; j < 5; ++j) {
#pragma unroll
        for (int kk = 0; kk < 4; ++kk) {
            const int it = j * 4 + kk, bb = it & 1;
            __syncthreads();
#pragma unroll
            for (int q = 0; q < 4; ++q)
                *(v4i*)&Bsm[bb][tid * 80 + ((q * 16) ^ ((tid & 3) << 4))] = breg[q];
            __syncthreads();
            if (it < 19) {   // prefetch next stage into regs
                const int nj = (kk == 3) ? j + 1 : j;
                const int nkk = (kk == 3) ? 0 : kk + 1;
                const signed char* bp = W1p + (size_t)nj * 131072 +
                                        (size_t)tid * 256 + nkk * 64;
#pragma unroll
                for (int q = 0; q < 4; ++q) breg[q] = *(const v4i*)(bp + q * 16);
            }
            // B fragments (shared across i)
            v4i bf[2][2];
#pragma unroll
            for (int nt = 0; nt < 2; ++nt)
#pragma unroll
                for (int ks = 0; ks < 2; ++ks) {
                    int hcol = wave * 64 + nt * 32 + lrow;
                    int kl = ks * 32 + lhalf * 16;
                    bf[nt][ks] = *(const v4i*)&Bsm[bb][hcol * 80 + (kl ^ ((hcol & 3) << 4))];
                }
#pragma unroll
            for (int i = 0; i <= 4 - j; ++i) {
                v4i af[2];
#pragma unroll
                for (int ks = 0; ks < 2; ++ks) {
                    int k = kk * 64 + ks * 32 + lhalf * 16;
                    af[ks] = *(const v4i*)&Asm[i * 8192 + lrow * 256 + (k ^ ((lrow & 7) << 4))];
                }
#pragma unroll
                for (int nt = 0; nt < 2; ++nt)
#pragma unroll
                    for (int ks = 0; ks < 2; ++ks)
                        acc[i + j][nt] = __builtin_amdgcn_mfma_i32_32x32x32_i8(
                            af[ks], bf[nt][ks], acc[i + j][nt], 0, 0, 0);
            }
        }
    }

    // epilogue: recombine (exact i32 -> f64), bias, LayerNorm, store f64
    const double scl[5] = {0x1p-13, 0x1p-20, 0x1p-27, 0x1p-34, 0x1p-41};
    double vv[2][16];
    int colc[2];
#pragma unroll
    for (int nt = 0; nt < 2; ++nt) {
        colc[nt] = wave * 64 + nt * 32 + lrow;
        double bcol = (double)b1[colc[nt]];
#pragma unroll
        for (int r = 0; r < 16; ++r) {
            double t = 0.0;
#pragma unroll
            for (int g = 0; g < 5; ++g) t = fma((double)acc[g][nt][r], scl[g], t);
            vv[nt][r] = t + bcol;
        }
    }
    double ps[16], pq[16];
#pragma unroll
    for (int r = 0; r < 16; ++r) {
        ps[r] = vv[0][r] + vv[1][r];
        pq[r] = vv[0][r] * vv[0][r] + vv[1][r] * vv[1][r];
    }
#pragma unroll
    for (int m = 1; m < 32; m <<= 1)
#pragma unroll
        for (int r = 0; r < 16; ++r) {
            ps[r] += shfl_xor_d(ps[r], m);
            pq[r] += shfl_xor_d(pq[r], m);
        }
    if (lrow == 0) {
#pragma unroll
        for (int r = 0; r < 16; ++r) {
            int rw = (r & 3) + 8 * (r >> 2) + 4 * lhalf;
            RS[wave][rw] = ps[r];
            RQ[wave][rw] = pq[r];
        }
    }
    __syncthreads();
    if (tid < 32) {
        double s = 0.0, q = 0.0;
#pragma unroll
        for (int w = 0; w < 8; ++w) { s += RS[w][tid]; q += RQ[w][tid]; }
        double mu = s * (1.0 / 512.0);
        double var = q * (1.0 / 512.0) - mu * mu;
        MUs[tid] = mu;
        IVs[tid] = 1.0 / sqrt(var + 1e-5);
    }
    __syncthreads();
#pragma unroll
    for (int nt = 0; nt < 2; ++nt) {
        int col = colc[nt];
        double gg = (double)g1[col], bb2 = (double)be1[col];
#pragma unroll
        for (int r = 0; r < 16; ++r) {
            int rw = (r & 3) + 8 * (r >> 2) + 4 * lhalf;
            double o = (vv[nt][r] - MUs[rw]) * IVs[rw] * gg + bb2;
            Hn[(size_t)(m0 + rw) * 512 + col] = o;
        }
    }
}

// ---------------------------------------------------------------------------
// GEMM2: Y = S @ W2^T + b2, LayerNorm(256). A = spikes (exact single plane),
// B = 5 W2 digit planes -> 5 i32 banks. Block 64x256, waves 2m x 4n.
// ---------------------------------------------------------------------------
__global__ __launch_bounds__(512, 2) void gemm2_i8(
    const signed char* __restrict__ S, const signed char* __restrict__ W2p,
    const float* __restrict__ b2, const float* __restrict__ g2,
    const float* __restrict__ be2, double* __restrict__ Yn) {
    __shared__ signed char Asm[64 * 512];           // 32768 B
    __shared__ signed char Bsm[2][256 * 144];       // 73728 B, [d][k128] pad 144
    __shared__ double RS[4][64], RQ[4][64];
    __shared__ double MUs[64], IVs[64];

    const int tid = threadIdx.x;
    const int wave = tid >> 6, lane = tid & 63, lrow = lane & 31, lhalf = lane >> 5;
    const int wm = wave >> 2, wn = wave & 3;
    const int m0 = blockIdx.x * 64;

    v16i acc[5][2];
#pragma unroll
    for (int g = 0; g < 5; ++g)
#pragma unroll
        for (int nt = 0; nt < 2; ++nt)
#pragma unroll
            for (int r = 0; r < 16; ++r) acc[g][nt][r] = 0;

    // stage A (spikes): [64][512], thread: row tid>>3, 64 bytes at (tid&7)*64
    {
        int r = tid >> 3, k0 = (tid & 7) * 64;
#pragma unroll
        for (int q = 0; q < 4; ++q) {
            int k = k0 + q * 16;
            v4i v = *(const v4i*)(S + (size_t)(m0 + r) * 512 + k);
            *(v4i*)&Asm[r * 512 + (k ^ ((r & 7) << 4))] = v;
        }
    }

    v4i breg[4];
    {   // prologue (j=0, kk=0): thread: d = tid>>1, 64 bytes at (tid&1)*64
        const signed char* bp = W2p + (size_t)(tid >> 1) * 512 + (tid & 1) * 64;
#pragma unroll
        for (int q = 0; q < 4; ++q) breg[q] = *(const v4i*)(bp + q * 16);
    }

#pragma unroll
    for (int j = 0; j < 5; ++j) {
#pragma unroll
        for (int kk = 0; kk < 4; ++kk) {
            const int it = j * 4 + kk, bb = it & 1;
            const int d = tid >> 1, klb = (tid & 1) * 64;
            __syncthreads();
#pragma unroll
            for (int q = 0; q < 4; ++q) {
                int kl = klb + q * 16;
                *(v4i*)&Bsm[bb][d * 144 + (kl ^ ((d & 7) << 4))] = breg[q];
            }
            __syncthreads();
            if (it < 19) {
                const int nj = (kk == 3) ? j + 1 : j;
                const int nkk = (kk == 3) ? 0 : kk + 1;
                const signed char* bp = W2p + (size_t)nj * 131072 +
                                        (size_t)(tid >> 1) * 512 + nkk * 128 + (tid & 1) * 64;
#pragma unroll
                for (int q = 0; q < 4; ++q) breg[q] = *(const v4i*)(bp + q * 16);
            }
            v4i bf[2][4];
#pragma unroll
            for (int nt = 0; nt < 2; ++nt)
#pragma unroll
                for (int ks = 0; ks < 4; ++ks) {
                    int dcol = wn * 64 + nt * 32 + lrow;
                    int kl = ks * 32 + lhalf * 16;
                    bf[nt][ks] = *(const v4i*)&Bsm[bb][dcol * 144 + (kl ^ ((dcol & 7) << 4))];
                }
            v4i af[4];
#pragma unroll
            for (int ks = 0; ks < 4; ++ks) {
                int arow = wm * 32 + lrow;
                int k = kk * 128 + ks * 32 + lhalf * 16;
                af[ks] = *(const v4i*)&Asm[arow * 512 + (k ^ ((arow & 7) << 4))];
            }
#pragma unroll
            for (int nt = 0; nt < 2; ++nt)
#pragma unroll
                for (int ks = 0; ks < 4; ++ks)
                    acc[j][nt] = __builtin_amdgcn_mfma_i32_32x32x32_i8(
                        af[ks], bf[nt][ks], acc[j][nt], 0, 0, 0);
        }
    }

    const double scl[5] = {0x1p-10, 0x1p-17, 0x1p-24, 0x1p-31, 0x1p-38};
    double vv[2][16];
    int colc[2];
#pragma unroll
    for (int nt = 0; nt < 2; ++nt) {
        colc[nt] = wn * 64 + nt * 32 + lrow;
        double bcol = (double)b2[colc[nt]];
#pragma unroll
        for (int r = 0; r < 16; ++r) {
            double t = 0.0;
#pragma unroll
            for (int g = 0; g < 5; ++g) t = fma((double)acc[g][nt][r], scl[g], t);
            vv[nt][r] = t + bcol;
        }
    }
    double ps[16], pq[16];
#pragma unroll
    for (int r = 0; r < 16; ++r) {
        ps[r] = vv[0][r] + vv[1][r];
        pq[r] = vv[0][r] * vv[0][r] + vv[1][r] * vv[1][r];
    }
#pragma unroll
    for (int m = 1; m < 32; m <<= 1)
#pragma unroll
        for (int r = 0; r < 16; ++r) {
            ps[r] += shfl_xor_d(ps[r], m);
            pq[r] += shfl_xor_d(pq[r], m);
        }
    if (lrow == 0) {
#pragma unroll
        for (int r = 0; r < 16; ++r) {
            int rw = wm * 32 + (r & 3) + 8 * (r >> 2) + 4 * lhalf;
            RS[wn][rw] = ps[r];
            RQ[wn][rw] = pq[r];
        }
    }
    __syncthreads();
    if (tid < 64) {
        double s = 0.0, q = 0.0;
#pragma unroll
        for (int w = 0; w < 4; ++w) { s += RS[w][tid]; q += RQ[w][tid]; }
        double mu = s * (1.0 / 256.0);
        double var = q * (1.0 / 256.0) - mu * mu;
        MUs[tid] = mu;
        IVs[tid] = 1.0 / sqrt(var + 1e-5);
    }
    __syncthreads();
#pragma unroll
    for (int nt = 0; nt < 2; ++nt) {
        int col = colc[nt];
        double gg = (double)g2[col], bb2 = (double)be2[col];
#pragma unroll
        for (int r = 0; r < 16; ++r) {
            int rw = wm * 32 + (r & 3) + 8 * (r >> 2) + 4 * lhalf;
            double o = (vv[nt][r] - MUs[rw]) * IVs[rw] * gg + bb2;
            Yn[(size_t)(m0 + rw) * 256 + col] = o;
        }
    }
}

// ---------------------------------------------------------------------------
// LIF1: fp64 recurrence over T, one lane per (b,h), depth-3 group prefetch.
// ---------------------------------------------------------------------------
__global__ __launch_bounds__(64) void lif1_k(const double* __restrict__ Hn,
                                             signed char* __restrict__ S) {
    int b = blockIdx.x >> 3;
    int h = (blockIdx.x & 7) * 64 + threadIdx.x;
    const double* src = Hn + (size_t)b * TT * HH + h;
    signed char* dst = S + (size_t)b * TT * HH + h;
    double v = 0.0;
    double buf[4][16];
#pragma unroll
    for (int gg = 0; gg < 3; ++gg)
#pragma unroll
        for (int t = 0; t < 16; ++t) buf[gg][t] = src[(size_t)(gg * 16 + t) * HH];
    for (int g4 = 0; g4 < 64; g4 += 4) {
#pragma unroll
        for (int u = 0; u < 4; ++u) {
            int g = g4 + u;
            if (g + 3 < 64) {
#pragma unroll
                for (int t = 0; t < 16; ++t)
                    buf[(u + 3) & 3][t] = src[(size_t)((g + 3) * 16 + t) * HH];
            }
#pragma unroll
            for (int t = 0; t < 16; ++t) {
                v += (buf[u][t] - v) * 0.5;
                bool sp = (v >= 1.0);
                dst[(size_t)(g * 16 + t) * HH] = sp ? 1 : 0;
                if (sp) v = 0.0;
            }
        }
    }
}

// ---------------------------------------------------------------------------
// LIF2 + residual: out = x + spike, fp64 recurrence, depth-3 prefetch.
// ---------------------------------------------------------------------------
__global__ __launch_bounds__(64) void lif2_k(const double* __restrict__ Yn,
                                             const float* __restrict__ X,
                                             float* __restrict__ out) {
    int b = blockIdx.x >> 2;
    int d = (blockIdx.x & 3) * 64 + threadIdx.x;
    const double* src = Yn + (size_t)b * TT * DD + d;
    const float* xs = X + (size_t)b * TT * DD + d;
    float* dst = out + (size_t)b * TT * DD + d;
    double v = 0.0;
    double bufy[4][16];
    float bufx[4][16];
#pragma unroll
    for (int gg = 0; gg < 3; ++gg)
#pragma unroll
        for (int t = 0; t < 16; ++t) {
            bufy[gg][t] = src[(size_t)(gg * 16 + t) * DD];
            bufx[gg][t] = xs[(size_t)(gg * 16 + t) * DD];
        }
    for (int g4 = 0; g4 < 64; g4 += 4) {
#pragma unroll
        for (int u = 0; u < 4; ++u) {
            int g = g4 + u;
            if (g + 3 < 64) {
#pragma unroll
                for (int t = 0; t < 16; ++t) {
                    bufy[(u + 3) & 3][t] = src[(size_t)((g + 3) * 16 + t) * DD];
                    bufx[(u + 3) & 3][t] = xs[(size_t)((g + 3) * 16 + t) * DD];
                }
            }
#pragma unroll
            for (int t = 0; t < 16; ++t) {
                v += (bufy[u][t] - v) * 0.5;
                bool sp = (v >= 1.0);
                dst[(size_t)(g * 16 + t) * DD] = bufx[u][t] + (sp ? 1.0f : 0.0f);
                if (sp) v = 0.0;
            }
        }
    }
}

extern "C" void kernel_launch(void* const* d_in, const int* in_sizes, int n_in,
                              void* d_out, int out_size, void* d_ws, size_t ws_size,
                              hipStream_t stream) {
    const float* x   = (const float*)d_in[0];
    const float* W1  = (const float*)d_in[1];
    const float* b1  = (const float*)d_in[2];
    const float* g1  = (const float*)d_in[3];
    const float* be1 = (const float*)d_in[4];
    const float* W2  = (const float*)d_in[5];
    const float* b2  = (const float*)d_in[6];
    const float* g2  = (const float*)d_in[7];
    const float* be2 = (const float*)d_in[8];
    float* out = (float*)d_out;

    char* ws = (char*)d_ws;
    signed char* W1p = (signed char*)ws;                        // 640 KB
    signed char* W2p = (signed char*)(ws + (1ull << 20));       // 640 KB
    signed char* Xp  = (signed char*)(ws + (2ull << 20));       // 40 MB (aliases Yn)
    double*      Yn  = (double*)(ws + (2ull << 20));            // 64 MB (aliases Xp)
    double*      Hn  = (double*)(ws + (66ull << 20));           // 128 MB
    signed char* Sb  = (signed char*)(ws + (194ull << 20));     // 16 MB
    // total 210 MB

    prep_w_k<<<dim3(512), dim3(256), 0, stream>>>(W1, W2, W1p, W2p);

    for (int c = 0; c < 2; ++c) {
        const float* xc = x + (size_t)c * CM * DD;
        float* outc = out + (size_t)c * CM * DD;
        split_x_k<<<dim3(8192), dim3(256), 0, stream>>>(xc, Xp);
        gemm1_i8<<<dim3(CM / 32), dim3(512), 0, stream>>>(Xp, W1p, b1, g1, be1, Hn);
        lif1_k<<<dim3(CB * 8), dim3(64), 0, stream>>>(Hn, Sb);
        gemm2_i8<<<dim3(CM / 64), dim3(512), 0, stream>>>(Sb, W2p, b2, g2, be2, Yn);
        lif2_k<<<dim3(CB * 4), dim3(64), 0, stream>>>(Yn, xc, outc);
    }
}